// Round 3
// baseline (190.801 us; speedup 1.0000x reference)
//
#include <hip/hip_runtime.h>
#include <math.h>

// Problem constants: B molecules, N=64 atoms, E=512 edges, R_CUT=10
#define SQRT_PI 1.7724538509055160273
#define SQRT_2  1.4142135623730950488
#define PI_OVER_2RC 0.15707963267948966

typedef double dbl4 __attribute__((ext_vector_type(4)));

__device__ __forceinline__ double bcast64(double v, int lane) {
    union { double d; unsigned int u[2]; } a, r;
    a.d = v;
    r.u[0] = __builtin_amdgcn_readlane(a.u[0], lane);
    r.u[1] = __builtin_amdgcn_readlane(a.u[1], lane);
    return r.d;
}

__device__ __forceinline__ double a_entry(int i, int j, const double* posd,
                                          const double* sig, const double* dg) {
    if (i == j) return dg[i];
    double dx = posd[3*i+0]-posd[3*j+0];
    double dy = posd[3*i+1]-posd[3*j+1];
    double dz = posd[3*i+2]-posd[3*j+2];
    double d  = sqrt(dx*dx+dy*dy+dz*dz);
    double g  = sqrt(sig[i]+sig[j]);
    return erf(d/(SQRT_2*g))/d;
}

// swap-aware MFMA: xv = A-side value, yv = B-side value
__device__ __forceinline__ dbl4 mfma64(int cS, double xv, double yv, dbl4 acc) {
    return cS ? __builtin_amdgcn_mfma_f64_16x16x4f64(yv, xv, acc, 0, 0, 0)
              : __builtin_amdgcn_mfma_f64_16x16x4f64(xv, yv, acc, 0, 0, 0);
}

// ---------------- fused kernel (single dispatch) ----------------
// one block (16 waves) per molecule.
// Inline MFMA-layout probe on waves 0-3 (8 hypotheses each, race-free slots).
// Gram: S = T W T^T via f64 MFMA, 10 symmetric tiles: heavy waves {0,5,10,15}
//   own a tile for all 8 chunks; 6 wave-pairs split a tile by chunk parity.
//   SIMD-balanced (320 MFMA/SIMD) under both rg%4 and rg>>2 mappings.
// Operand delivery: 4-deep software-pipelined ds_read_b64 batches (needs the
//   128-VGPR budget from __launch_bounds__(1024,4)).
// Identity: out = u (since (I+SA)u = t0) -> no S*s epilogue; S,P alias Ta,Tb.
__global__ __launch_bounds__(1024, 4)
void k_fused(const float* __restrict__ pos, const float* __restrict__ T,
             const int* __restrict__ eidx, const float* __restrict__ nattr,
             const float* __restrict__ eneg, const float* __restrict__ qtot,
             const float* __restrict__ hard, const float* __restrict__ covr,
             const int* __restrict__ an, float* __restrict__ outp)
{
    const int m = blockIdx.x, tid = threadIdx.x;
    const int jl = tid & 63;        // lane
    const int rg = tid >> 6;        // wave id 0..15
    const int kl = jl >> 4, ml = jl & 15;

    __shared__ double R[2*64*66];   // Ta,Tb | SB,Pm   (67584 B)
    __shared__ double AB[64*65];    // A then M/L      (33280 B)
    __shared__ double w_sl[512];
    __shared__ double posd[192], sig_s[64], dg_s[64], eneg_s[64];
    __shared__ double t0a_s[64], t0b_s[64], ga_s[64], gb_s[64];
    __shared__ double ua_s[64], ub_s[64], sa_s[64], sb_s[64];
    __shared__ double dinv_s[64], dvec_s[64];
    __shared__ double lam_sh, sw_sh;
    __shared__ int fl_w[4];

    double* const Ta = R;           // [64][66] f64, gram phase
    double* const Tb = R + 64*66;   // [64][66] f64 (w-scaled), gram phase
    double* const SB = R;           // [64][66] f64, S (post-gram .. end)
    double* const Pm = R + 64*66;   // [64][66] f64, P = A*S

    const float* Tm = T + (size_t)m*64*512;
    const int srow = tid >> 4, sc4 = (tid & 15) * 4;

    // earliest possible chunk-0 prefetch
    float4 v = *(const float4*)&Tm[srow*512 + sc4];

    // ---- preamble: inline layout probe (waves 0-3) + per-atom loads (waves 4-6) ----
    if (rg < 4) {
        const double af1 = (double)(jl + 1),  bf1 = (double)(jl + 65);
        const double af2 = (double)(1 + ((jl*7 + 3) % 61));
        const double bf2 = (double)(2 + ((jl*13 + 5) % 53));
        dbl4 c1 = {0.0,0.0,0.0,0.0}, c2 = {0.0,0.0,0.0,0.0};
        c1 = __builtin_amdgcn_mfma_f64_16x16x4f64(af1, bf1, c1, 0, 0, 0);
        c2 = __builtin_amdgcn_mfma_f64_16x16x4f64(af2, bf2, c2, 0, 0, 0);
        int myh = -1;
        for (int hh = 0; hh < 8; ++hh) {
            const int h = rg*8 + hh;
            const int pS = h >> 4, pA = (h >> 3) & 1, pB = (h >> 2) & 1, pD = h & 3;
            bool ok = true;
            #pragma unroll
            for (int r = 0; r < 4; ++r) {
                int row, col;
                const int v0 = 4*kl + r, v1 = kl + 4*r;
                if (pD == 0)      { row = v0; col = ml; }
                else if (pD == 1) { row = v1; col = ml; }
                else if (pD == 2) { row = ml; col = v0; }
                else              { row = ml; col = v1; }
                double r1 = 0.0, r2 = 0.0;
                #pragma unroll
                for (int k = 0; k < 4; ++k) {
                    const int la = pA ? (row*4 + k) : (row + 16*k);
                    const int lb = pB ? (col*4 + k) : (col + 16*k);
                    if (pS == 0) {
                        r1 += (double)(la + 1) * (double)(lb + 65);
                        r2 += (double)(1 + ((la*7+3) % 61)) * (double)(2 + ((lb*13+5) % 53));
                    } else {
                        r1 += (double)(lb + 1) * (double)(la + 65);
                        r2 += (double)(1 + ((lb*7+3) % 61)) * (double)(2 + ((la*13+5) % 53));
                    }
                }
                if (c1[r] != r1 || c2[r] != r2) ok = false;
            }
            if (__ballot(ok) == ~0ull) myh = h;
        }
        if (jl == 0) fl_w[rg] = myh;
    } else if (tid >= 256 && tid < 320) {
        const int at = tid - 256;
        posd[3*at+0] = (double)pos[(m*64+at)*3+0];
        posd[3*at+1] = (double)pos[(m*64+at)*3+1];
        posd[3*at+2] = (double)pos[(m*64+at)*3+2];
        double r = (double)covr[an[m*64+at]];
        sig_s[at] = r*r;
        const float* np_ = nattr + (size_t)(m*64+at)*10;
        float best = np_[0]; int bi = 0;
        #pragma unroll
        for (int k = 1; k < 10; ++k) { float vv = np_[k]; if (vv > best) { best = vv; bi = k; } }
        dg_s[at] = (double)hard[bi] + 1.0/(SQRT_PI*r);
    } else if (tid >= 320 && tid < 384) {
        const int at = tid - 320;
        eneg_s[at] = (double)eneg[m*64 + at];
    }
    __syncthreads();   // B1: probe results + atom data ready

    // layout constants (every thread)
    int hbest = max(max(fl_w[0], fl_w[1]), max(fl_w[2], fl_w[3]));
    if (hbest < 0) hbest = 1;   // unreachable on gfx950; standard-layout guess
    const int cS = hbest >> 4, cA = (hbest >> 3) & 1, cB = (hbest >> 2) & 1, cD = hbest & 3;
    const int aRow = cA ? (jl >> 2) : ml;
    const int aK   = cA ? (jl & 3)  : kl;
    const int bRow = cB ? (jl >> 2) : ml;
    const int bK   = cB ? (jl & 3)  : kl;
    int drow[4], dcol[4];
    #pragma unroll
    for (int r = 0; r < 4; ++r) {
        const int v0 = 4*kl + r, v1 = kl + 4*r;
        if (cD == 0)      { drow[r] = v0; dcol[r] = ml; }
        else if (cD == 1) { drow[r] = v1; dcol[r] = ml; }
        else if (cD == 2) { drow[r] = ml; dcol[r] = v0; }
        else              { drow[r] = ml; dcol[r] = v1; }
    }

    // ---- edge weights w (tid<512), consumed after first in-loop barrier ----
    if (tid < 512) {
        const int a0 = eidx[(size_t)m*1024 + tid];
        const int a1 = eidx[(size_t)m*1024 + 512 + tid];
        double dx = posd[3*a0+0]-posd[3*a1+0];
        double dy = posd[3*a0+1]-posd[3*a1+1];
        double dz = posd[3*a0+2]-posd[3*a1+2];
        double d  = sqrt(dx*dx+dy*dy+dz*dz);
        w_sl[tid] = 1.0 / (1.0/cos(PI_OVER_2RC*d) - 1.0);
    }

    // ---- Gram work assignment: 10 tiles, heavy waves {0,5,10,15} ----
    // WT: tile per wave; WM: 0=all chunks, 1=even chunks, 2=odd chunks
    const int TP_[10] = {0,1,1,2,2,2,3,3,3,3};
    const int TQ_[10] = {0,0,1,0,1,2,0,1,2,3};
    const int WT[16] = {0,4,4,5,5,1,6,6,7,7,2,8,8,9,9,3};
    const int WM[16] = {0,1,2,1,2,0,1,2,1,2,0,1,2,1,2,0};
    const int myt = WT[rg], wm = WM[rg];
    const int tp = TP_[myt], tq = TQ_[myt];
    const double* ta_b = &Ta[(size_t)(tp*16 + aRow)*66 + aK];
    const double* tb_b = &Tb[(size_t)(tq*16 + bRow)*66 + bK];
    dbl4 vacc = {0.0, 0.0, 0.0, 0.0};
    double t0b_p = 0.0;
    double areg[4];

    #pragma unroll
    for (int cc = 0; cc < 8; ++cc) {
        __syncthreads();                           // prev chunk's Ta/Tb reads done (cc=0: w ready)
        const double w0 = w_sl[cc*64 + sc4+0];
        const double w1 = w_sl[cc*64 + sc4+1];
        const double w2 = w_sl[cc*64 + sc4+2];
        const double w3 = w_sl[cc*64 + sc4+3];
        const double d0 = (double)v.x, d1 = (double)v.y;
        const double d2 = (double)v.z, d3 = (double)v.w;
        {
            double2 p0; p0.x = d0; p0.y = d1;
            double2 p1; p1.x = d2; p1.y = d3;
            *(double2*)&Ta[srow*66 + sc4]     = p0;
            *(double2*)&Ta[srow*66 + sc4 + 2] = p1;
            double2 q0; q0.x = w0*d0; q0.y = w1*d1;
            double2 q1; q1.x = w2*d2; q1.y = w3*d3;
            *(double2*)&Tb[srow*66 + sc4]     = q0;
            *(double2*)&Tb[srow*66 + sc4 + 2] = q1;
        }
        t0b_p += d0*w0 + d1*w1 + d2*w2 + d3*w3;    // t0b = T·w folded into staging
        if (cc < 7) v = *(const float4*)&Tm[srow*512 + (cc+1)*64 + sc4];
        __syncthreads();                           // staged data visible
        if (cc == 0 && tid >= 128 && tid < 192) {  // wave2 (idle this chunk): sum(w)
            const int ll = tid - 128;
            double s = 0.0;
            #pragma unroll
            for (int c = 0; c < 8; ++c) s += w_sl[c*64 + ll];
            #pragma unroll
            for (int off = 32; off > 0; off >>= 1) s += __shfl_down(s, off);
            if (ll == 0) sw_sh = s;
        }
        if (cc < 4) {                              // A-build under MFMA shadow
            const int i = rg + 16*cc;
            double av = a_entry(i, jl, posd, sig_s, dg_s);
            areg[cc] = av;
            AB[i*65 + jl] = av;
        }
        const bool act = (wm == 0) || (wm == 1 ? ((cc & 1) == 0) : ((cc & 1) == 1));
        if (act) {
            // 4-deep software-pipelined operand delivery
            double xc[4], yc[4];
            #pragma unroll
            for (int q = 0; q < 4; ++q) { xc[q] = ta_b[q*4]; yc[q] = tb_b[q*4]; }
            #pragma unroll
            for (int kb = 0; kb < 4; ++kb) {
                double xn[4], yn[4];
                if (kb < 3) {
                    #pragma unroll
                    for (int q = 0; q < 4; ++q) {
                        xn[q] = ta_b[(kb*4+4+q)*4];
                        yn[q] = tb_b[(kb*4+4+q)*4];
                    }
                }
                #pragma unroll
                for (int q = 0; q < 4; ++q) vacc = mfma64(cS, xc[q], yc[q], vacc);
                if (kb < 3) {
                    #pragma unroll
                    for (int q = 0; q < 4; ++q) { xc[q] = xn[q]; yc[q] = yn[q]; }
                }
            }
        }
    }
    __syncthreads();   // gram reads done; R becomes SB/Pm

    // ---- S assembly: full/even writers first, odd-partial adders second ----
    if (wm != 2) {
        #pragma unroll
        for (int r = 0; r < 4; ++r) {
            const int ri = tp*16 + drow[r], cj = tq*16 + dcol[r];
            SB[ri*66 + cj] = vacc[r];
            if (tp != tq) SB[cj*66 + ri] = vacc[r];
        }
    }
    {   // t0b: reduce 16 column-group partials per row (register-only)
        double t = t0b_p;
        t += __shfl_down(t, 8, 16);
        t += __shfl_down(t, 4, 16);
        t += __shfl_down(t, 2, 16);
        t += __shfl_down(t, 1, 16);
        if ((tid & 15) == 0) t0b_s[tid >> 4] = t;
    }
    __syncthreads();
    if (wm == 2) {
        #pragma unroll
        for (int r = 0; r < 4; ++r) {
            const int ri = tp*16 + drow[r], cj = tq*16 + dcol[r];
            const double vv = vacc[r];
            SB[ri*66 + cj] += vv;
            if (tp != tq) SB[cj*66 + ri] += vv;
        }
    }
    __syncthreads();   // S complete

    // ---- GEMM1: P = A·S (16 tiles / 16 waves) + t0a hidden underneath ----
    const int ti = rg >> 2, tj = rg & 3;
    {
        const double* xb = &AB[(size_t)(ti*16 + aRow)*65 + aK];
        const double* yb = &SB[(size_t)bK*66 + tj*16 + bRow];
        dbl4 pacc = {0.0, 0.0, 0.0, 0.0};
        double xc[4], yc[4];
        #pragma unroll
        for (int q = 0; q < 4; ++q) { xc[q] = xb[q*4]; yc[q] = yb[q*264]; }
        #pragma unroll
        for (int kb = 0; kb < 4; ++kb) {
            double xn[4], yn[4];
            if (kb < 3) {
                #pragma unroll
                for (int q = 0; q < 4; ++q) {
                    xn[q] = xb[(kb*4+4+q)*4];
                    yn[q] = yb[(size_t)(kb*4+4+q)*264];
                }
            }
            #pragma unroll
            for (int q = 0; q < 4; ++q) pacc = mfma64(cS, xc[q], yc[q], pacc);
            if (kb < 3) {
                #pragma unroll
                for (int q = 0; q < 4; ++q) { xc[q] = xn[q]; yc[q] = yn[q]; }
            }
        }
        #pragma unroll
        for (int r = 0; r < 4; ++r)
            Pm[(ti*16 + drow[r])*66 + tj*16 + dcol[r]] = pacc[r];
        // t0a = -S·eneg (VALU, hidden under the MFMAs above)
        const int c16 = tid & 15, row16 = tid >> 4;
        double a = 0.0;
        #pragma unroll
        for (int kk = 0; kk < 4; ++kk)
            a += SB[row16*66 + 4*c16 + kk] * eneg_s[4*c16 + kk];
        a += __shfl_down(a, 8, 16);
        a += __shfl_down(a, 4, 16);
        a += __shfl_down(a, 2, 16);
        a += __shfl_down(a, 1, 16);
        if (c16 == 0) t0a_s[row16] = -a;
    }
    __syncthreads();   // Pm + t0a ready

    // ---- GEMM2: M = A + P·A (overwrite AB) + g = A·t0 hidden underneath ----
    {
        dbl4 macc;
        #pragma unroll
        for (int r = 0; r < 4; ++r)
            macc[r] = AB[(ti*16 + drow[r])*65 + tj*16 + dcol[r]];
        const double* xb = &Pm[(size_t)(ti*16 + aRow)*66 + aK];
        const double* yb = &AB[(size_t)bK*65 + tj*16 + bRow];
        double xc[4], yc[4];
        #pragma unroll
        for (int q = 0; q < 4; ++q) { xc[q] = xb[q*4]; yc[q] = yb[q*260]; }
        #pragma unroll
        for (int kb = 0; kb < 4; ++kb) {
            double xn[4], yn[4];
            if (kb < 3) {
                #pragma unroll
                for (int q = 0; q < 4; ++q) {
                    xn[q] = xb[(kb*4+4+q)*4];
                    yn[q] = yb[(size_t)(kb*4+4+q)*260];
                }
            }
            #pragma unroll
            for (int q = 0; q < 4; ++q) macc = mfma64(cS, xc[q], yc[q], macc);
            if (kb < 3) {
                #pragma unroll
                for (int q = 0; q < 4; ++q) { xc[q] = xn[q]; yc[q] = yn[q]; }
            }
        }
        // g = A·t0 via areg wave reduction (VALU, hidden under MFMAs)
        {
            double ra[4], rb[4];
            const double ta = t0a_s[jl], tb = t0b_s[jl];
            #pragma unroll
            for (int p = 0; p < 4; ++p) { ra[p] = areg[p]*ta; rb[p] = areg[p]*tb; }
            #pragma unroll
            for (int off = 32; off > 0; off >>= 1) {
                #pragma unroll
                for (int p = 0; p < 4; ++p) {
                    ra[p] += __shfl_down(ra[p], off);
                    rb[p] += __shfl_down(rb[p], off);
                }
            }
            if (jl == 0) {
                #pragma unroll
                for (int p = 0; p < 4; ++p) { ga_s[rg+16*p] = ra[p]; gb_s[rg+16*p] = rb[p]; }
            }
        }
        __syncthreads();   // all GEMM2 AB reads done
        #pragma unroll
        for (int r = 0; r < 4; ++r)
            AB[(ti*16 + drow[r])*65 + tj*16 + dcol[r]] = macc[r];
    }
    __syncthreads();

    // ---- blocked LDL^T: wave0 panel factor + trailing updates (verified) ----
    for (int pb = 0; pb < 4; ++pb) {
        const int kb = pb*16;
        if (tid < 64) {
            const int i = tid;
            double pr[16];
            #pragma unroll
            for (int c = 0; c < 16; ++c) pr[c] = AB[i*65 + kb + c];
            #pragma unroll
            for (int c = 0; c < 16; ++c) {
                const int k = kb + c;
                const double Dk = bcast64(pr[c], k);
                const double di = 1.0 / Dk;
                if (i == k) { dinv_s[k] = di; dvec_s[k] = Dk; }
                const double lik = pr[c] * di;
                #pragma unroll
                for (int j = c+1; j < 16; ++j) {
                    const double mkj = bcast64(pr[j], k);
                    if (i > k) pr[j] -= lik * mkj;
                }
                if (i > k) pr[c] = lik;
            }
            #pragma unroll
            for (int c = 0; c < 16; ++c) AB[i*65 + kb + c] = pr[c];
        }
        __syncthreads();
        const int lim = kb + 16;
        if (lim < 64) {
            double tacc[4] = {0.0, 0.0, 0.0, 0.0};
            #pragma unroll 4
            for (int c = 0; c < 16; ++c) {
                double lbv = AB[jl*65 + kb + c] * dvec_s[kb + c];
                #pragma unroll
                for (int p = 0; p < 4; ++p)
                    tacc[p] += AB[(rg+16*p)*65 + kb + c] * lbv;
            }
            if (jl >= lim) {
                #pragma unroll
                for (int p = 0; p < 4; ++p) {
                    int i = rg + 16*p;
                    if (i >= lim) AB[i*65 + jl] -= tacc[p];
                }
            }
        }
        __syncthreads();
    }

    // ---- solves in wave0: L h = g ; h *= D^-1 ; L^T u = h ----
    if (tid < 64) {
        const int i = tid;
        double ha = ga_s[i], hb = gb_s[i];
        #pragma unroll
        for (int j = 0; j < 63; ++j) {
            double xa = bcast64(ha, j), xb = bcast64(hb, j);
            double lij = (i > j) ? AB[i*65+j] : 0.0;
            ha -= lij*xa; hb -= lij*xb;
        }
        double di = dinv_s[i];
        ha *= di; hb *= di;
        #pragma unroll
        for (int j = 63; j > 0; --j) {
            double xa = bcast64(ha, j), xb = bcast64(hb, j);
            double lji = (i < j) ? AB[j*65+i] : 0.0;
            ha -= lji*xa; hb -= lji*xb;
        }
        ua_s[i] = ha; ub_s[i] = hb;
    }
    __syncthreads();

    // ---- s = A·u via areg wave reduction (needed only for lambda scalars) ----
    {
        double ra[4], rb[4];
        const double uaj = ua_s[jl], ubj = ub_s[jl];
        #pragma unroll
        for (int p = 0; p < 4; ++p) { ra[p] = areg[p]*uaj; rb[p] = areg[p]*ubj; }
        #pragma unroll
        for (int off = 32; off > 0; off >>= 1) {
            #pragma unroll
            for (int p = 0; p < 4; ++p) {
                ra[p] += __shfl_down(ra[p], off);
                rb[p] += __shfl_down(rb[p], off);
            }
        }
        if (jl == 0) {
            #pragma unroll
            for (int p = 0; p < 4; ++p) {
                sa_s[rg + 16*p] = ra[p];
                sb_s[rg + 16*p] = rb[p];
            }
        }
    }
    __syncthreads();

    // ---- lambda + output:  out = ua - lambda*ub  (identity: p1 = ua, p2 = ub) ----
    if (tid < 64) {
        double d1 = (eneg_s[tid] + sa_s[tid]) * t0b_s[tid];
        double d2 = sb_s[tid] * t0b_s[tid];
        #pragma unroll
        for (int off = 32; off > 0; off >>= 1) {
            d1 += __shfl_down(d1, off);
            d2 += __shfl_down(d2, off);
        }
        if (tid == 0) {
            double sY = -d1;
            double sZ = sw_sh - d2;
            lam_sh = ((double)qtot[m] - sY) / (1.0 - sZ);
        }
    }
    __syncthreads();
    if (tid < 64)
        outp[m*64 + tid] = (float)(ua_s[tid] - lam_sh*ub_s[tid]);
}

extern "C" void kernel_launch(void* const* d_in, const int* in_sizes, int n_in,
                              void* d_out, int out_size, void* d_ws, size_t ws_size,
                              hipStream_t stream) {
    const float* pos  = (const float*)d_in[0];
    const float* T    = (const float*)d_in[1];
    const float* eneg = (const float*)d_in[2];
    const float* nat  = (const float*)d_in[3];
    const float* qt   = (const float*)d_in[4];
    // d_in[5] 'p' unused
    const float* hard = (const float*)d_in[6];
    const float* covr = (const float*)d_in[7];
    const int*   an   = (const int*)d_in[8];
    const int*   eidx = (const int*)d_in[9];
    float* outp = (float*)d_out;
    (void)n_in; (void)out_size; (void)d_ws; (void)ws_size;

    const int B = in_sizes[4];
    k_fused<<<dim3(B), dim3(1024), 0, stream>>>(pos, T, eidx, nat, eneg, qt,
                                                hard, covr, an, outp);
}

// Round 4
// 162.648 us; speedup vs baseline: 1.1731x; 1.1731x over previous
//
#include <hip/hip_runtime.h>
#include <math.h>

// Problem constants: B molecules, N=64 atoms, E=512 edges, R_CUT=10
#define SQRT_PI 1.7724538509055160273
#define SQRT_2  1.4142135623730950488
#define PI_OVER_2RC 0.15707963267948966

typedef double dbl4 __attribute__((ext_vector_type(4)));

// ws layout (doubles): flags fl[0..4] only.

__device__ __forceinline__ double bcast64(double v, int lane) {
    union { double d; unsigned int u[2]; } a, r;
    a.d = v;
    r.u[0] = __builtin_amdgcn_readlane(a.u[0], lane);
    r.u[1] = __builtin_amdgcn_readlane(a.u[1], lane);
    return r.d;
}

__device__ __forceinline__ double a_entry(int i, int j, const double* posd,
                                          const double* sig, const double* dg) {
    if (i == j) return dg[i];
    double dx = posd[3*i+0]-posd[3*j+0];
    double dy = posd[3*i+1]-posd[3*j+1];
    double dz = posd[3*i+2]-posd[3*j+2];
    double d  = sqrt(dx*dx+dy*dy+dz*dz);
    double g  = sqrt(sig[i]+sig[j]);
    return erf(d/(SQRT_2*g))/d;
}

// swap-aware MFMA: xv = A-side value, yv = B-side value
__device__ __forceinline__ dbl4 mfma64(int cS, double xv, double yv, dbl4 acc) {
    return cS ? __builtin_amdgcn_mfma_f64_16x16x4f64(yv, xv, acc, 0, 0, 0)
              : __builtin_amdgcn_mfma_f64_16x16x4f64(xv, yv, acc, 0, 0, 0);
}

// ---------------- K0: f64-MFMA layout probe (injective, dual value-set) ----------------
__global__ __launch_bounds__(64)
void k0_probe(double* __restrict__ fl)
{
    const int l = threadIdx.x;
    const int kl = l >> 4, ml = l & 15;
    const double af1 = (double)(l + 1),  bf1 = (double)(l + 65);
    const double af2 = (double)(1 + ((l*7 + 3) % 61));
    const double bf2 = (double)(2 + ((l*13 + 5) % 53));
    dbl4 c1 = {0.0,0.0,0.0,0.0}, c2 = {0.0,0.0,0.0,0.0};
    c1 = __builtin_amdgcn_mfma_f64_16x16x4f64(af1, bf1, c1, 0, 0, 0);
    c2 = __builtin_amdgcn_mfma_f64_16x16x4f64(af2, bf2, c2, 0, 0, 0);
    int best = -1;
    for (int h = 0; h < 32; ++h) {
        if (best >= 0) break;
        const int cS = h >> 4, cA = (h >> 3) & 1, cB = (h >> 2) & 1, cD = h & 3;
        bool ok = true;
        #pragma unroll
        for (int r = 0; r < 4; ++r) {
            int row, col;
            const int v0 = 4*kl + r, v1 = kl + 4*r;
            if (cD == 0)      { row = v0; col = ml; }
            else if (cD == 1) { row = v1; col = ml; }
            else if (cD == 2) { row = ml; col = v0; }
            else              { row = ml; col = v1; }
            double r1 = 0.0, r2 = 0.0;
            #pragma unroll
            for (int k = 0; k < 4; ++k) {
                const int la = cA ? (row*4 + k) : (row + 16*k);
                const int lb = cB ? (col*4 + k) : (col + 16*k);
                if (cS == 0) {
                    r1 += (double)(la + 1) * (double)(lb + 65);
                    r2 += (double)(1 + ((la*7+3) % 61)) * (double)(2 + ((lb*13+5) % 53));
                } else {
                    r1 += (double)(lb + 1) * (double)(la + 65);
                    r2 += (double)(1 + ((lb*7+3) % 61)) * (double)(2 + ((la*13+5) % 53));
                }
            }
            if (c1[r] != r1 || c2[r] != r2) ok = false;
        }
        if (__ballot(ok) == ~0ull) best = h;
    }
    if (l == 0) {
        fl[0] = (best >= 0) ? 1.0 : 0.0;
        fl[1] = (double)((best >= 0) ? (best >> 4)      : 0);
        fl[2] = (double)((best >= 0) ? ((best >> 3) & 1) : 0);
        fl[3] = (double)((best >= 0) ? ((best >> 2) & 1) : 0);
        fl[4] = (double)((best >= 0) ? (best & 3)        : 0);
    }
}

// ---------------- fused kernel ----------------
// one block (16 waves) per molecule.
// Gram: S = T W T^T, 10 non-redundant symmetric tiles: diag tiles on waves
//   {0,5,10,15} (all 8 chunks), 6 off-diag tiles on wave-pairs split by chunk
//   parity. 320 MFMA/SIMD under both rg%4 and rg>>2 wave->SIMD mappings.
//   Tile map via uniform switch (NO memory-indexed tables -> no promote-alloca).
// Prefetch of next T chunk issued AFTER the publish barrier so the implicit
//   vmcnt(0) drain at the next chunk-top barrier lands under the MFMA window.
// Identity: out = u (since (I+SA)u = t0) -> no S*s epilogue; S,P alias Ta,Tb.
__global__ __launch_bounds__(1024)
void k_fused(const float* __restrict__ pos, const float* __restrict__ T,
             const int* __restrict__ eidx, const float* __restrict__ nattr,
             const float* __restrict__ eneg, const float* __restrict__ qtot,
             const float* __restrict__ hard, const float* __restrict__ covr,
             const int* __restrict__ an, const double* __restrict__ flq,
             float* __restrict__ outp)
{
    const int m = blockIdx.x, tid = threadIdx.x;
    const int jl = tid & 63;        // lane
    const int rg = tid >> 6;        // wave id 0..15
    const int kl = jl >> 4, ml = jl & 15;

    __shared__ double R[2*64*66];   // Ta,Tb | SB,Pm   (67584 B)
    __shared__ double AB[64*65];    // A then M/L      (33280 B)
    __shared__ double w_sl[512];
    __shared__ double posd[192], sig_s[64], dg_s[64], eneg_s[64];
    __shared__ double t0a_s[64], t0b_s[64], ga_s[64], gb_s[64];
    __shared__ double ua_s[64], ub_s[64], sa_s[64], sb_s[64];
    __shared__ double dinv_s[64], dvec_s[64];
    __shared__ double lam_sh, sw_sh;

    double* const Ta = R;           // [64][66] f64, gram phase
    double* const Tb = R + 64*66;   // [64][66] f64 (w-scaled), gram phase
    double* const SB = R;           // [64][66] f64, S (post-gram .. end)
    double* const Pm = R + 64*66;   // [64][66] f64, P = A*S

    // probed MFMA layout (k0 ran before us; deterministic)
    const int cS = (int)flq[1], cA = (int)flq[2], cB = (int)flq[3], cD = (int)flq[4];
    const int aRow = cA ? (jl >> 2) : ml;
    const int aK   = cA ? (jl & 3)  : kl;
    const int bRow = cB ? (jl >> 2) : ml;
    const int bK   = cB ? (jl & 3)  : kl;
    int drow[4], dcol[4];
    #pragma unroll
    for (int r = 0; r < 4; ++r) {
        const int v0 = 4*kl + r, v1 = kl + 4*r;
        if (cD == 0)      { drow[r] = v0; dcol[r] = ml; }
        else if (cD == 1) { drow[r] = v1; dcol[r] = ml; }
        else if (cD == 2) { drow[r] = ml; dcol[r] = v0; }
        else              { drow[r] = ml; dcol[r] = v1; }
    }

    const float* Tm = T + (size_t)m*64*512;
    const int srow = tid >> 4, sc4 = (tid & 15) * 4;

    // earliest possible chunk-0 prefetch
    float4 v = *(const float4*)&Tm[srow*512 + sc4];

    // ---- phase A: per-atom loads ----
    if (tid < 64) {
        posd[3*tid+0] = (double)pos[(m*64+tid)*3+0];
        posd[3*tid+1] = (double)pos[(m*64+tid)*3+1];
        posd[3*tid+2] = (double)pos[(m*64+tid)*3+2];
        double r = (double)covr[an[m*64+tid]];
        sig_s[tid] = r*r;
        const float* np_ = nattr + (size_t)(m*64+tid)*10;
        float best = np_[0]; int bi = 0;
        #pragma unroll
        for (int k = 1; k < 10; ++k) { float vv = np_[k]; if (vv > best) { best = vv; bi = k; } }
        dg_s[tid] = (double)hard[bi] + 1.0/(SQRT_PI*r);
    } else if (tid < 128) {
        int ll = tid - 64;
        eneg_s[ll] = (double)eneg[m*64 + ll];
    }
    __syncthreads();

    // ---- phase B: edge weights w (tid<512); visibility via gram loop-top barrier ----
    if (tid < 512) {
        const int a0 = eidx[(size_t)m*1024 + tid];
        const int a1 = eidx[(size_t)m*1024 + 512 + tid];
        double dx = posd[3*a0+0]-posd[3*a1+0];
        double dy = posd[3*a0+1]-posd[3*a1+1];
        double dz = posd[3*a0+2]-posd[3*a1+2];
        double d  = sqrt(dx*dx+dy*dy+dz*dz);
        w_sl[tid] = 1.0 / (1.0/cos(PI_OVER_2RC*d) - 1.0);
    }

    // ---- Gram work assignment: 10 tiles, diag waves {0,5,10,15} full,
    //      off-diag pairs split by chunk parity. wm: 0=all, 1=even cc, 2=odd cc.
    int tp, tq, wm;
    switch (rg) {
        case 0:  tp=0; tq=0; wm=0; break;
        case 5:  tp=1; tq=1; wm=0; break;
        case 10: tp=2; tq=2; wm=0; break;
        case 15: tp=3; tq=3; wm=0; break;
        case 1:  tp=1; tq=0; wm=1; break;
        case 2:  tp=1; tq=0; wm=2; break;
        case 3:  tp=2; tq=0; wm=1; break;
        case 4:  tp=2; tq=0; wm=2; break;
        case 6:  tp=2; tq=1; wm=1; break;
        case 7:  tp=2; tq=1; wm=2; break;
        case 8:  tp=3; tq=0; wm=1; break;
        case 9:  tp=3; tq=0; wm=2; break;
        case 11: tp=3; tq=1; wm=1; break;
        case 12: tp=3; tq=1; wm=2; break;
        case 13: tp=3; tq=2; wm=1; break;
        default: tp=3; tq=2; wm=2; break;   // rg == 14
    }
    const double* ta_b = &Ta[(size_t)(tp*16 + aRow)*66 + aK];
    const double* tb_b = &Tb[(size_t)(tq*16 + bRow)*66 + bK];
    dbl4 vacc = {0.0, 0.0, 0.0, 0.0};
    double t0b_p = 0.0;
    double areg[4];

    #pragma unroll
    for (int cc = 0; cc < 8; ++cc) {
        __syncthreads();                           // prev chunk's Ta/Tb reads done (cc=0: w ready)
        const double w0 = w_sl[cc*64 + sc4+0];
        const double w1 = w_sl[cc*64 + sc4+1];
        const double w2 = w_sl[cc*64 + sc4+2];
        const double w3 = w_sl[cc*64 + sc4+3];
        const double d0 = (double)v.x, d1 = (double)v.y;
        const double d2 = (double)v.z, d3 = (double)v.w;
        {
            double2 p0; p0.x = d0; p0.y = d1;
            double2 p1; p1.x = d2; p1.y = d3;
            *(double2*)&Ta[srow*66 + sc4]     = p0;
            *(double2*)&Ta[srow*66 + sc4 + 2] = p1;
            double2 q0; q0.x = w0*d0; q0.y = w1*d1;
            double2 q1; q1.x = w2*d2; q1.y = w3*d3;
            *(double2*)&Tb[srow*66 + sc4]     = q0;
            *(double2*)&Tb[srow*66 + sc4 + 2] = q1;
        }
        t0b_p += d0*w0 + d1*w1 + d2*w2 + d3*w3;    // t0b = T·w folded into staging
        __syncthreads();                           // staged data visible
        // prefetch next chunk AFTER the barrier: its vmcnt(0) drain happens at
        // the NEXT chunk-top barrier, hidden under this chunk's MFMA window.
        if (cc < 7) v = *(const float4*)&Tm[srow*512 + (cc+1)*64 + sc4];
        if (cc == 0 && tid >= 128 && tid < 192) {  // wave2 (parity-idle at cc=0): sum(w)
            const int ll = tid - 128;
            double s = 0.0;
            #pragma unroll
            for (int c = 0; c < 8; ++c) s += w_sl[c*64 + ll];
            #pragma unroll
            for (int off = 32; off > 0; off >>= 1) s += __shfl_down(s, off);
            if (ll == 0) sw_sh = s;
        }
        if (cc < 4) {                              // A-build under MFMA shadow
            const int i = rg + 16*cc;
            double av = a_entry(i, jl, posd, sig_s, dg_s);
            areg[cc] = av;
            AB[i*65 + jl] = av;
        }
        const bool act = (wm == 0) || (wm == 1 ? ((cc & 1) == 0) : ((cc & 1) == 1));
        if (act) {
            #pragma unroll
            for (int kk = 0; kk < 16; ++kk)
                vacc = mfma64(cS, ta_b[kk*4], tb_b[kk*4], vacc);
        }
    }
    __syncthreads();   // gram reads done; R becomes SB/Pm

    // ---- S assembly: full/even writers first, odd-partial adders second ----
    if (wm != 2) {
        #pragma unroll
        for (int r = 0; r < 4; ++r) {
            const int ri = tp*16 + drow[r], cj = tq*16 + dcol[r];
            SB[ri*66 + cj] = vacc[r];
            if (tp != tq) SB[cj*66 + ri] = vacc[r];
        }
    }
    {   // t0b: reduce 16 column-group partials per row (register-only)
        double t = t0b_p;
        t += __shfl_down(t, 8, 16);
        t += __shfl_down(t, 4, 16);
        t += __shfl_down(t, 2, 16);
        t += __shfl_down(t, 1, 16);
        if ((tid & 15) == 0) t0b_s[tid >> 4] = t;
    }
    __syncthreads();
    if (wm == 2) {
        #pragma unroll
        for (int r = 0; r < 4; ++r) {
            const int ri = tp*16 + drow[r], cj = tq*16 + dcol[r];
            const double vv = vacc[r];
            SB[ri*66 + cj] += vv;
            if (tp != tq) SB[cj*66 + ri] += vv;
        }
    }
    __syncthreads();   // S complete

    // ---- t0a = -S·eneg (LDS-S, 16-lane reduce) ----
    {
        const int c16 = tid & 15, row16 = tid >> 4;
        double a = 0.0;
        #pragma unroll
        for (int kk = 0; kk < 4; ++kk)
            a += SB[row16*66 + 4*c16 + kk] * eneg_s[4*c16 + kk];
        a += __shfl_down(a, 8, 16);
        a += __shfl_down(a, 4, 16);
        a += __shfl_down(a, 2, 16);
        a += __shfl_down(a, 1, 16);
        if (c16 == 0) t0a_s[row16] = -a;
    }
    __syncthreads();

    // ---- g = A·t0 via areg wave reduction ----
    {
        double ra[4], rb[4];
        const double ta = t0a_s[jl], tb = t0b_s[jl];
        #pragma unroll
        for (int p = 0; p < 4; ++p) { ra[p] = areg[p]*ta; rb[p] = areg[p]*tb; }
        #pragma unroll
        for (int off = 32; off > 0; off >>= 1) {
            #pragma unroll
            for (int p = 0; p < 4; ++p) {
                ra[p] += __shfl_down(ra[p], off);
                rb[p] += __shfl_down(rb[p], off);
            }
        }
        if (jl == 0) {
            #pragma unroll
            for (int p = 0; p < 4; ++p) { ga_s[rg+16*p] = ra[p]; gb_s[rg+16*p] = rb[p]; }
        }
    }
    __syncthreads();

    // ---- GEMM1: P = A·S (16 tiles / 16 waves, immediate-offset operands) ----
    const int ti = rg >> 2, tj = rg & 3;
    {
        const double* xb = &AB[(size_t)(ti*16 + aRow)*65 + aK];
        const double* yb = &SB[(size_t)bK*66 + tj*16 + bRow];
        dbl4 pacc = {0.0, 0.0, 0.0, 0.0};
        #pragma unroll
        for (int kk = 0; kk < 16; ++kk)
            pacc = mfma64(cS, xb[kk*4], yb[kk*264], pacc);
        #pragma unroll
        for (int r = 0; r < 4; ++r)
            Pm[(ti*16 + drow[r])*66 + tj*16 + dcol[r]] = pacc[r];   // Pm != SB, no barrier needed
    }
    __syncthreads();   // P visible

    // ---- GEMM2: M = A + P·A, overwrite AB ----
    {
        dbl4 macc;
        #pragma unroll
        for (int r = 0; r < 4; ++r)
            macc[r] = AB[(ti*16 + drow[r])*65 + tj*16 + dcol[r]];
        const double* xb = &Pm[(size_t)(ti*16 + aRow)*66 + aK];
        const double* yb = &AB[(size_t)bK*65 + tj*16 + bRow];
        #pragma unroll
        for (int kk = 0; kk < 16; ++kk)
            macc = mfma64(cS, xb[kk*4], yb[kk*260], macc);
        __syncthreads();   // all GEMM2 AB reads done
        #pragma unroll
        for (int r = 0; r < 4; ++r)
            AB[(ti*16 + drow[r])*65 + tj*16 + dcol[r]] = macc[r];
    }
    __syncthreads();

    // ---- blocked LDL^T: wave0 panel factor + trailing updates (verified) ----
    for (int pb = 0; pb < 4; ++pb) {
        const int kb = pb*16;
        if (tid < 64) {
            const int i = tid;
            double pr[16];
            #pragma unroll
            for (int c = 0; c < 16; ++c) pr[c] = AB[i*65 + kb + c];
            #pragma unroll
            for (int c = 0; c < 16; ++c) {
                const int k = kb + c;
                const double Dk = bcast64(pr[c], k);
                const double di = 1.0 / Dk;
                if (i == k) { dinv_s[k] = di; dvec_s[k] = Dk; }
                const double lik = pr[c] * di;
                #pragma unroll
                for (int j = c+1; j < 16; ++j) {
                    const double mkj = bcast64(pr[j], k);
                    if (i > k) pr[j] -= lik * mkj;
                }
                if (i > k) pr[c] = lik;
            }
            #pragma unroll
            for (int c = 0; c < 16; ++c) AB[i*65 + kb + c] = pr[c];
        }
        __syncthreads();
        const int lim = kb + 16;
        if (lim < 64) {
            double tacc[4] = {0.0, 0.0, 0.0, 0.0};
            #pragma unroll 4
            for (int c = 0; c < 16; ++c) {
                double lbv = AB[jl*65 + kb + c] * dvec_s[kb + c];
                #pragma unroll
                for (int p = 0; p < 4; ++p)
                    tacc[p] += AB[(rg+16*p)*65 + kb + c] * lbv;
            }
            if (jl >= lim) {
                #pragma unroll
                for (int p = 0; p < 4; ++p) {
                    int i = rg + 16*p;
                    if (i >= lim) AB[i*65 + jl] -= tacc[p];
                }
            }
        }
        __syncthreads();
    }

    // ---- solves: wave0 does RHS a, wave1 does RHS b (independent chains) ----
    if (tid < 128) {
        const int i = jl;
        double h = (rg == 0) ? ga_s[i] : gb_s[i];
        #pragma unroll
        for (int j = 0; j < 63; ++j) {
            double x = bcast64(h, j);
            double lij = (i > j) ? AB[i*65+j] : 0.0;
            h -= lij*x;
        }
        h *= dinv_s[i];
        #pragma unroll
        for (int j = 63; j > 0; --j) {
            double x = bcast64(h, j);
            double lji = (i < j) ? AB[j*65+i] : 0.0;
            h -= lji*x;
        }
        if (rg == 0) ua_s[i] = h; else ub_s[i] = h;
    }
    __syncthreads();

    // ---- s = A·u via areg wave reduction (needed only for lambda scalars) ----
    {
        double ra[4], rb[4];
        const double uaj = ua_s[jl], ubj = ub_s[jl];
        #pragma unroll
        for (int p = 0; p < 4; ++p) { ra[p] = areg[p]*uaj; rb[p] = areg[p]*ubj; }
        #pragma unroll
        for (int off = 32; off > 0; off >>= 1) {
            #pragma unroll
            for (int p = 0; p < 4; ++p) {
                ra[p] += __shfl_down(ra[p], off);
                rb[p] += __shfl_down(rb[p], off);
            }
        }
        if (jl == 0) {
            #pragma unroll
            for (int p = 0; p < 4; ++p) {
                sa_s[rg + 16*p] = ra[p];
                sb_s[rg + 16*p] = rb[p];
            }
        }
    }
    __syncthreads();

    // ---- lambda + output:  out = ua - lambda*ub  (identity: p1 = ua, p2 = ub) ----
    if (tid < 64) {
        double d1 = (eneg_s[tid] + sa_s[tid]) * t0b_s[tid];
        double d2 = sb_s[tid] * t0b_s[tid];
        #pragma unroll
        for (int off = 32; off > 0; off >>= 1) {
            d1 += __shfl_down(d1, off);
            d2 += __shfl_down(d2, off);
        }
        if (tid == 0) {
            double sY = -d1;
            double sZ = sw_sh - d2;
            lam_sh = ((double)qtot[m] - sY) / (1.0 - sZ);
        }
    }
    __syncthreads();
    if (tid < 64)
        outp[m*64 + tid] = (float)(ua_s[tid] - lam_sh*ub_s[tid]);
}

extern "C" void kernel_launch(void* const* d_in, const int* in_sizes, int n_in,
                              void* d_out, int out_size, void* d_ws, size_t ws_size,
                              hipStream_t stream) {
    const float* pos  = (const float*)d_in[0];
    const float* T    = (const float*)d_in[1];
    const float* eneg = (const float*)d_in[2];
    const float* nat  = (const float*)d_in[3];
    const float* qt   = (const float*)d_in[4];
    // d_in[5] 'p' unused
    const float* hard = (const float*)d_in[6];
    const float* covr = (const float*)d_in[7];
    const int*   an   = (const int*)d_in[8];
    const int*   eidx = (const int*)d_in[9];
    float* outp = (float*)d_out;
    (void)n_in; (void)out_size; (void)ws_size;

    const int B = in_sizes[4];
    double* ws = (double*)d_ws;   // 5 doubles (probe flags)

    k0_probe<<<dim3(1), dim3(64), 0, stream>>>(ws);
    k_fused<<<dim3(B), dim3(1024), 0, stream>>>(pos, T, eidx, nat, eneg, qt,
                                                hard, covr, an, ws, outp);
}

// Round 6
// 159.923 us; speedup vs baseline: 1.1931x; 1.0170x over previous
//
#include <hip/hip_runtime.h>
#include <math.h>

// Problem constants: B molecules, N=64 atoms, E=512 edges, R_CUT=10
#define SQRT_PI 1.7724538509055160273
#define SQRT_2  1.4142135623730950488
#define PI_OVER_2RC 0.15707963267948966

typedef double dbl4 __attribute__((ext_vector_type(4)));

// ws layout (doubles): flags fl[0..4] only.

__device__ __forceinline__ double bcast64(double v, int lane) {
    union { double d; unsigned int u[2]; } a, r;
    a.d = v;
    r.u[0] = __builtin_amdgcn_readlane(a.u[0], lane);
    r.u[1] = __builtin_amdgcn_readlane(a.u[1], lane);
    return r.d;
}

__device__ __forceinline__ double a_entry(int i, int j, const double* posd,
                                          const double* sig, const double* dg) {
    if (i == j) return dg[i];
    double dx = posd[3*i+0]-posd[3*j+0];
    double dy = posd[3*i+1]-posd[3*j+1];
    double dz = posd[3*i+2]-posd[3*j+2];
    double d  = sqrt(dx*dx+dy*dy+dz*dz);
    double g  = sqrt(sig[i]+sig[j]);
    return erf(d/(SQRT_2*g))/d;
}

// swap-aware MFMA: xv = A-side value, yv = B-side value
__device__ __forceinline__ dbl4 mfma64(int cS, double xv, double yv, dbl4 acc) {
    return cS ? __builtin_amdgcn_mfma_f64_16x16x4f64(yv, xv, acc, 0, 0, 0)
              : __builtin_amdgcn_mfma_f64_16x16x4f64(xv, yv, acc, 0, 0, 0);
}

// ---------------- K0: f64-MFMA layout probe (injective, dual value-set) ----------------
__global__ __launch_bounds__(64)
void k0_probe(double* __restrict__ fl)
{
    const int l = threadIdx.x;
    const int kl = l >> 4, ml = l & 15;
    const double af1 = (double)(l + 1),  bf1 = (double)(l + 65);
    const double af2 = (double)(1 + ((l*7 + 3) % 61));
    const double bf2 = (double)(2 + ((l*13 + 5) % 53));
    dbl4 c1 = {0.0,0.0,0.0,0.0}, c2 = {0.0,0.0,0.0,0.0};
    c1 = __builtin_amdgcn_mfma_f64_16x16x4f64(af1, bf1, c1, 0, 0, 0);
    c2 = __builtin_amdgcn_mfma_f64_16x16x4f64(af2, bf2, c2, 0, 0, 0);
    int best = -1;
    for (int h = 0; h < 32; ++h) {
        if (best >= 0) break;
        const int cS = h >> 4, cA = (h >> 3) & 1, cB = (h >> 2) & 1, cD = h & 3;
        bool ok = true;
        #pragma unroll
        for (int r = 0; r < 4; ++r) {
            int row, col;
            const int v0 = 4*kl + r, v1 = kl + 4*r;
            if (cD == 0)      { row = v0; col = ml; }
            else if (cD == 1) { row = v1; col = ml; }
            else if (cD == 2) { row = ml; col = v0; }
            else              { row = ml; col = v1; }
            double r1 = 0.0, r2 = 0.0;
            #pragma unroll
            for (int k = 0; k < 4; ++k) {
                const int la = cA ? (row*4 + k) : (row + 16*k);
                const int lb = cB ? (col*4 + k) : (col + 16*k);
                if (cS == 0) {
                    r1 += (double)(la + 1) * (double)(lb + 65);
                    r2 += (double)(1 + ((la*7+3) % 61)) * (double)(2 + ((lb*13+5) % 53));
                } else {
                    r1 += (double)(lb + 1) * (double)(la + 65);
                    r2 += (double)(1 + ((lb*7+3) % 61)) * (double)(2 + ((la*13+5) % 53));
                }
            }
            if (c1[r] != r1 || c2[r] != r2) ok = false;
        }
        if (__ballot(ok) == ~0ull) best = h;
    }
    if (l == 0) {
        fl[0] = (best >= 0) ? 1.0 : 0.0;
        fl[1] = (double)((best >= 0) ? (best >> 4)      : 0);
        fl[2] = (double)((best >= 0) ? ((best >> 3) & 1) : 0);
        fl[3] = (double)((best >= 0) ? ((best >> 2) & 1) : 0);
        fl[4] = (double)((best >= 0) ? (best & 3)        : 0);
    }
}

// ---------------- fused kernel ----------------
// one block (16 waves) per molecule.
// Gram: S = T W T^T, 10 non-redundant symmetric tiles (diag on waves
//   {0,5,10,15}, off-diag pairs split by chunk parity), dual accumulators to
//   break the per-wave MFMA dependency chain.
// t0a hidden under GEMM1, g hidden under GEMM2 (VALU under MFMA shadow).
// Identity 1: out = u (since (I+SA)u = t0) -> no S*s epilogue.
// Identity 2: sa.t0b = ua.gb, sb.t0b = ub.gb (A symmetric) -> no s=A*u phase.
// Lambda broadcast via lam_sh + barrier (NOT in-register bcast of a
//   conditionally-assigned value: that miscompiled to undef in round 5).
__global__ __launch_bounds__(1024)
void k_fused(const float* __restrict__ pos, const float* __restrict__ T,
             const int* __restrict__ eidx, const float* __restrict__ nattr,
             const float* __restrict__ eneg, const float* __restrict__ qtot,
             const float* __restrict__ hard, const float* __restrict__ covr,
             const int* __restrict__ an, const double* __restrict__ flq,
             float* __restrict__ outp)
{
    const int m = blockIdx.x, tid = threadIdx.x;
    const int jl = tid & 63;        // lane
    const int rg = tid >> 6;        // wave id 0..15
    const int kl = jl >> 4, ml = jl & 15;

    __shared__ double R[2*64*66];   // Ta,Tb | SB,Pm   (67584 B)
    __shared__ double AB[64*65];    // A then M/L      (33280 B)
    __shared__ double w_sl[512];
    __shared__ double posd[192], sig_s[64], dg_s[64], eneg_s[64];
    __shared__ double t0a_s[64], t0b_s[64], ga_s[64], gb_s[64];
    __shared__ double ua_s[64], ub_s[64];
    __shared__ double dinv_s[64], dvec_s[64];
    __shared__ double lam_sh, sw_sh;

    double* const Ta = R;           // [64][66] f64, gram phase
    double* const Tb = R + 64*66;   // [64][66] f64 (w-scaled), gram phase
    double* const SB = R;           // [64][66] f64, S (post-gram .. end)
    double* const Pm = R + 64*66;   // [64][66] f64, P = A*S

    // probed MFMA layout (k0 ran before us; deterministic)
    const int cS = (int)flq[1], cA = (int)flq[2], cB = (int)flq[3], cD = (int)flq[4];
    const int aRow = cA ? (jl >> 2) : ml;
    const int aK   = cA ? (jl & 3)  : kl;
    const int bRow = cB ? (jl >> 2) : ml;
    const int bK   = cB ? (jl & 3)  : kl;
    int drow[4], dcol[4];
    #pragma unroll
    for (int r = 0; r < 4; ++r) {
        const int v0 = 4*kl + r, v1 = kl + 4*r;
        if (cD == 0)      { drow[r] = v0; dcol[r] = ml; }
        else if (cD == 1) { drow[r] = v1; dcol[r] = ml; }
        else if (cD == 2) { drow[r] = ml; dcol[r] = v0; }
        else              { drow[r] = ml; dcol[r] = v1; }
    }

    const float* Tm = T + (size_t)m*64*512;
    const int srow = tid >> 4, sc4 = (tid & 15) * 4;

    // earliest possible chunk-0 prefetch
    float4 v = *(const float4*)&Tm[srow*512 + sc4];

    // ---- phase A: per-atom loads ----
    if (tid < 64) {
        posd[3*tid+0] = (double)pos[(m*64+tid)*3+0];
        posd[3*tid+1] = (double)pos[(m*64+tid)*3+1];
        posd[3*tid+2] = (double)pos[(m*64+tid)*3+2];
        double r = (double)covr[an[m*64+tid]];
        sig_s[tid] = r*r;
        const float* np_ = nattr + (size_t)(m*64+tid)*10;
        float best = np_[0]; int bi = 0;
        #pragma unroll
        for (int k = 1; k < 10; ++k) { float vv = np_[k]; if (vv > best) { best = vv; bi = k; } }
        dg_s[tid] = (double)hard[bi] + 1.0/(SQRT_PI*r);
    } else if (tid < 128) {
        int ll = tid - 64;
        eneg_s[ll] = (double)eneg[m*64 + ll];
    }
    __syncthreads();

    // ---- phase B: edge weights w (tid<512); visibility via gram loop-top barrier ----
    if (tid < 512) {
        const int a0 = eidx[(size_t)m*1024 + tid];
        const int a1 = eidx[(size_t)m*1024 + 512 + tid];
        double dx = posd[3*a0+0]-posd[3*a1+0];
        double dy = posd[3*a0+1]-posd[3*a1+1];
        double dz = posd[3*a0+2]-posd[3*a1+2];
        double d  = sqrt(dx*dx+dy*dy+dz*dz);
        w_sl[tid] = 1.0 / (1.0/cos(PI_OVER_2RC*d) - 1.0);
    }

    // ---- Gram work assignment: 10 tiles, diag waves {0,5,10,15} full,
    //      off-diag pairs split by chunk parity. wm: 0=all, 1=even cc, 2=odd cc.
    int tp, tq, wm;
    switch (rg) {
        case 0:  tp=0; tq=0; wm=0; break;
        case 5:  tp=1; tq=1; wm=0; break;
        case 10: tp=2; tq=2; wm=0; break;
        case 15: tp=3; tq=3; wm=0; break;
        case 1:  tp=1; tq=0; wm=1; break;
        case 2:  tp=1; tq=0; wm=2; break;
        case 3:  tp=2; tq=0; wm=1; break;
        case 4:  tp=2; tq=0; wm=2; break;
        case 6:  tp=2; tq=1; wm=1; break;
        case 7:  tp=2; tq=1; wm=2; break;
        case 8:  tp=3; tq=0; wm=1; break;
        case 9:  tp=3; tq=0; wm=2; break;
        case 11: tp=3; tq=1; wm=1; break;
        case 12: tp=3; tq=1; wm=2; break;
        case 13: tp=3; tq=2; wm=1; break;
        default: tp=3; tq=2; wm=2; break;   // rg == 14
    }
    const double* ta_b = &Ta[(size_t)(tp*16 + aRow)*66 + aK];
    const double* tb_b = &Tb[(size_t)(tq*16 + bRow)*66 + bK];
    dbl4 vacc0 = {0.0, 0.0, 0.0, 0.0};
    dbl4 vacc1 = {0.0, 0.0, 0.0, 0.0};
    double t0b_p = 0.0;
    double areg[4];

    #pragma unroll
    for (int cc = 0; cc < 8; ++cc) {
        __syncthreads();                           // prev chunk's Ta/Tb reads done (cc=0: w ready)
        const double w0 = w_sl[cc*64 + sc4+0];
        const double w1 = w_sl[cc*64 + sc4+1];
        const double w2 = w_sl[cc*64 + sc4+2];
        const double w3 = w_sl[cc*64 + sc4+3];
        const double d0 = (double)v.x, d1 = (double)v.y;
        const double d2 = (double)v.z, d3 = (double)v.w;
        {
            double2 p0; p0.x = d0; p0.y = d1;
            double2 p1; p1.x = d2; p1.y = d3;
            *(double2*)&Ta[srow*66 + sc4]     = p0;
            *(double2*)&Ta[srow*66 + sc4 + 2] = p1;
            double2 q0; q0.x = w0*d0; q0.y = w1*d1;
            double2 q1; q1.x = w2*d2; q1.y = w3*d3;
            *(double2*)&Tb[srow*66 + sc4]     = q0;
            *(double2*)&Tb[srow*66 + sc4 + 2] = q1;
        }
        t0b_p += d0*w0 + d1*w1 + d2*w2 + d3*w3;    // t0b = T·w folded into staging
        __syncthreads();                           // staged data visible
        // prefetch next chunk AFTER the barrier: its vmcnt(0) drain happens at
        // the NEXT chunk-top barrier, hidden under this chunk's MFMA window.
        if (cc < 7) v = *(const float4*)&Tm[srow*512 + (cc+1)*64 + sc4];
        if (cc == 0 && tid >= 128 && tid < 192) {  // wave2 (parity-idle at cc=0): sum(w)
            const int ll = tid - 128;
            double s = 0.0;
            #pragma unroll
            for (int c = 0; c < 8; ++c) s += w_sl[c*64 + ll];
            #pragma unroll
            for (int off = 32; off > 0; off >>= 1) s += __shfl_down(s, off);
            if (ll == 0) sw_sh = s;
        }
        if (cc < 4) {                              // A-build under MFMA shadow
            const int i = rg + 16*cc;
            double av = a_entry(i, jl, posd, sig_s, dg_s);
            areg[cc] = av;
            AB[i*65 + jl] = av;
        }
        const bool act = (wm == 0) || (wm == 1 ? ((cc & 1) == 0) : ((cc & 1) == 1));
        if (act) {
            #pragma unroll
            for (int kk = 0; kk < 16; kk += 2) {
                vacc0 = mfma64(cS, ta_b[kk*4],     tb_b[kk*4],     vacc0);
                vacc1 = mfma64(cS, ta_b[(kk+1)*4], tb_b[(kk+1)*4], vacc1);
            }
        }
    }
    __syncthreads();   // gram reads done; R becomes SB/Pm

    // ---- S assembly: full/even writers first, odd-partial adders second ----
    if (wm != 2) {
        #pragma unroll
        for (int r = 0; r < 4; ++r) {
            const int ri = tp*16 + drow[r], cj = tq*16 + dcol[r];
            const double vv = vacc0[r] + vacc1[r];
            SB[ri*66 + cj] = vv;
            if (tp != tq) SB[cj*66 + ri] = vv;
        }
    }
    {   // t0b: reduce 16 column-group partials per row (register-only)
        double t = t0b_p;
        t += __shfl_down(t, 8, 16);
        t += __shfl_down(t, 4, 16);
        t += __shfl_down(t, 2, 16);
        t += __shfl_down(t, 1, 16);
        if ((tid & 15) == 0) t0b_s[tid >> 4] = t;
    }
    __syncthreads();
    if (wm == 2) {
        #pragma unroll
        for (int r = 0; r < 4; ++r) {
            const int ri = tp*16 + drow[r], cj = tq*16 + dcol[r];
            const double vv = vacc0[r] + vacc1[r];
            SB[ri*66 + cj] += vv;
            if (tp != tq) SB[cj*66 + ri] += vv;
        }
    }
    __syncthreads();   // S complete

    // ---- GEMM1: P = A·S (16 tiles / 16 waves) with t0a = -S·eneg underneath ----
    const int ti = rg >> 2, tj = rg & 3;
    {
        const double* xb = &AB[(size_t)(ti*16 + aRow)*65 + aK];
        const double* yb = &SB[(size_t)bK*66 + tj*16 + bRow];
        dbl4 pacc0 = {0.0, 0.0, 0.0, 0.0};
        dbl4 pacc1 = {0.0, 0.0, 0.0, 0.0};
        #pragma unroll
        for (int kk = 0; kk < 16; kk += 2) {
            pacc0 = mfma64(cS, xb[kk*4],     yb[(size_t)kk*264],     pacc0);
            pacc1 = mfma64(cS, xb[(kk+1)*4], yb[(size_t)(kk+1)*264], pacc1);
        }
        // t0a = -S·eneg (VALU, hidden under the MFMA shadow)
        {
            const int c16 = tid & 15, row16 = tid >> 4;
            double a = 0.0;
            #pragma unroll
            for (int kk = 0; kk < 4; ++kk)
                a += SB[row16*66 + 4*c16 + kk] * eneg_s[4*c16 + kk];
            a += __shfl_down(a, 8, 16);
            a += __shfl_down(a, 4, 16);
            a += __shfl_down(a, 2, 16);
            a += __shfl_down(a, 1, 16);
            if (c16 == 0) t0a_s[row16] = -a;
        }
        #pragma unroll
        for (int r = 0; r < 4; ++r)
            Pm[(ti*16 + drow[r])*66 + tj*16 + dcol[r]] = pacc0[r] + pacc1[r];
    }
    __syncthreads();   // Pm + t0a ready

    // ---- GEMM2: M = A + P·A (overwrite AB) with g = A·t0 underneath ----
    {
        dbl4 macc0;
        #pragma unroll
        for (int r = 0; r < 4; ++r)
            macc0[r] = AB[(ti*16 + drow[r])*65 + tj*16 + dcol[r]];
        dbl4 macc1 = {0.0, 0.0, 0.0, 0.0};
        const double* xb = &Pm[(size_t)(ti*16 + aRow)*66 + aK];
        const double* yb = &AB[(size_t)bK*65 + tj*16 + bRow];
        #pragma unroll
        for (int kk = 0; kk < 16; kk += 2) {
            macc0 = mfma64(cS, xb[kk*4],     yb[(size_t)kk*260],     macc0);
            macc1 = mfma64(cS, xb[(kk+1)*4], yb[(size_t)(kk+1)*260], macc1);
        }
        // g = A·t0 via areg wave reduction (VALU, hidden under MFMA shadow)
        {
            double ra[4], rb[4];
            const double ta = t0a_s[jl], tb = t0b_s[jl];
            #pragma unroll
            for (int p = 0; p < 4; ++p) { ra[p] = areg[p]*ta; rb[p] = areg[p]*tb; }
            #pragma unroll
            for (int off = 32; off > 0; off >>= 1) {
                #pragma unroll
                for (int p = 0; p < 4; ++p) {
                    ra[p] += __shfl_down(ra[p], off);
                    rb[p] += __shfl_down(rb[p], off);
                }
            }
            if (jl == 0) {
                #pragma unroll
                for (int p = 0; p < 4; ++p) { ga_s[rg+16*p] = ra[p]; gb_s[rg+16*p] = rb[p]; }
            }
        }
        __syncthreads();   // all GEMM2 AB reads done
        #pragma unroll
        for (int r = 0; r < 4; ++r)
            AB[(ti*16 + drow[r])*65 + tj*16 + dcol[r]] = macc0[r] + macc1[r];
    }
    __syncthreads();

    // ---- blocked LDL^T: wave0 panel factor + trailing updates (verified) ----
    for (int pb = 0; pb < 4; ++pb) {
        const int kb = pb*16;
        if (tid < 64) {
            const int i = tid;
            double pr[16];
            #pragma unroll
            for (int c = 0; c < 16; ++c) pr[c] = AB[i*65 + kb + c];
            #pragma unroll
            for (int c = 0; c < 16; ++c) {
                const int k = kb + c;
                const double Dk = bcast64(pr[c], k);
                const double di = 1.0 / Dk;
                if (i == k) { dinv_s[k] = di; dvec_s[k] = Dk; }
                const double lik = pr[c] * di;
                #pragma unroll
                for (int j = c+1; j < 16; ++j) {
                    const double mkj = bcast64(pr[j], k);
                    if (i > k) pr[j] -= lik * mkj;
                }
                if (i > k) pr[c] = lik;
            }
            #pragma unroll
            for (int c = 0; c < 16; ++c) AB[i*65 + kb + c] = pr[c];
        }
        __syncthreads();
        const int lim = kb + 16;
        if (lim < 64) {
            double tacc[4] = {0.0, 0.0, 0.0, 0.0};
            #pragma unroll 4
            for (int c = 0; c < 16; ++c) {
                double lbv = AB[jl*65 + kb + c] * dvec_s[kb + c];
                #pragma unroll
                for (int p = 0; p < 4; ++p)
                    tacc[p] += AB[(rg+16*p)*65 + kb + c] * lbv;
            }
            if (jl >= lim) {
                #pragma unroll
                for (int p = 0; p < 4; ++p) {
                    int i = rg + 16*p;
                    if (i >= lim) AB[i*65 + jl] -= tacc[p];
                }
            }
        }
        __syncthreads();
    }

    // ---- solves: wave0 does RHS a, wave1 does RHS b (independent chains) ----
    if (tid < 128) {
        const int i = jl;
        double h = (rg == 0) ? ga_s[i] : gb_s[i];
        #pragma unroll
        for (int j = 0; j < 63; ++j) {
            double x = bcast64(h, j);
            double lij = (i > j) ? AB[i*65+j] : 0.0;
            h -= lij*x;
        }
        h *= dinv_s[i];
        #pragma unroll
        for (int j = 63; j > 0; --j) {
            double x = bcast64(h, j);
            double lji = (i < j) ? AB[j*65+i] : 0.0;
            h -= lji*x;
        }
        if (rg == 0) ua_s[i] = h; else ub_s[i] = h;
    }
    __syncthreads();

    // ---- lambda (identities: sa.t0b = ua.gb, sb.t0b = ub.gb), via lam_sh ----
    if (tid < 64) {
        const double ua = ua_s[tid], ub = ub_s[tid], gbv = gb_s[tid];
        double d1 = eneg_s[tid]*t0b_s[tid] + ua*gbv;   // = (eneg + sa)·t0b termwise
        double d2 = ub*gbv;                            // = sb·t0b termwise
        #pragma unroll
        for (int off = 32; off > 0; off >>= 1) {
            d1 += __shfl_down(d1, off);
            d2 += __shfl_down(d2, off);
        }
        if (tid == 0) {
            double sY = -d1;
            double sZ = sw_sh - d2;
            lam_sh = ((double)qtot[m] - sY) / (1.0 - sZ);
        }
    }
    __syncthreads();
    if (tid < 64)
        outp[m*64 + tid] = (float)(ua_s[tid] - lam_sh*ub_s[tid]);
}

extern "C" void kernel_launch(void* const* d_in, const int* in_sizes, int n_in,
                              void* d_out, int out_size, void* d_ws, size_t ws_size,
                              hipStream_t stream) {
    const float* pos  = (const float*)d_in[0];
    const float* T    = (const float*)d_in[1];
    const float* eneg = (const float*)d_in[2];
    const float* nat  = (const float*)d_in[3];
    const float* qt   = (const float*)d_in[4];
    // d_in[5] 'p' unused
    const float* hard = (const float*)d_in[6];
    const float* covr = (const float*)d_in[7];
    const int*   an   = (const int*)d_in[8];
    const int*   eidx = (const int*)d_in[9];
    float* outp = (float*)d_out;
    (void)n_in; (void)out_size; (void)ws_size;

    const int B = in_sizes[4];
    double* ws = (double*)d_ws;   // 5 doubles (probe flags)

    k0_probe<<<dim3(1), dim3(64), 0, stream>>>(ws);
    k_fused<<<dim3(B), dim3(1024), 0, stream>>>(pos, T, eidx, nat, eneg, qt,
                                                hard, covr, an, ws, outp);
}